// Round 13
// baseline (238.222 us; speedup 1.0000x reference)
//
#include <hip/hip_runtime.h>
#include <hip/hip_bf16.h>
#include <cstdint>

#define DEV __device__ __forceinline__

typedef __attribute__((ext_vector_type(8))) __bf16 bf16x8;
typedef __attribute__((ext_vector_type(4))) float f32x4;
typedef __attribute__((ext_vector_type(16))) float f32x16;

// fp32 -> bf16 via HW cvt (single v_cvt instruction)
DEV uint16_t f2b(float f) {
  __hip_bfloat16 h = __float2bfloat16(f);
  return *(uint16_t*)&h;
}
// pack two floats into a bf16x2 word
DEV uint32_t pkbf2(float a, float b) {
  return (uint32_t)f2b(a) | ((uint32_t)f2b(b) << 16);
}

// async global->LDS, 16B per lane. LDS base must be wave-uniform; HW writes
// base + lane*16. Global source address is per-lane.
DEV void gload_lds16(const void* g, void* l) {
  __builtin_amdgcn_global_load_lds(
      (const __attribute__((address_space(1))) void*)g,
      (__attribute__((address_space(3))) void*)l, 16, 0, 0);
}

// scale a bf16x8 by a constant (via fp32, RNE back to bf16)
DEV bf16x8 scale8(bf16x8 v, float sc) {
  union { bf16x8 b; uint16_t u[8]; } in, out;
  in.b = v;
#pragma unroll
  for (int i = 0; i < 8; i++) {
    float x = __uint_as_float(((uint32_t)in.u[i]) << 16);
    out.u[i] = f2b(x * sc);
  }
  return out.b;
}

// ---------------------------------------------------------------- cast x -> bf16
__global__ __launch_bounds__(256) void cast_bf16_kernel(
    const float* __restrict__ src, uint16_t* __restrict__ dst, int n4) {
  int i = blockIdx.x * 256 + threadIdx.x;
  if (i < n4) {
    float4 v = ((const float4*)src)[i];
    uint2 r;
    r.x = pkbf2(v.x, v.y);
    r.y = pkbf2(v.z, v.w);
    ((uint2*)dst)[i] = r;
  }
}

// ------------------------------------------- weight transpose fp32[R][C] -> bf16[C][R]
__global__ __launch_bounds__(256) void transpose_w(
    const float* __restrict__ src, uint16_t* __restrict__ dst, int R, int C) {
  __shared__ float t[32][33];
  int c0 = blockIdx.x * 32, r0 = blockIdx.y * 32;
  int tx = threadIdx.x & 31, ty = threadIdx.x >> 5;  // 32 x 8
#pragma unroll
  for (int i = 0; i < 4; i++)
    t[ty + 8 * i][tx] = src[(size_t)(r0 + ty + 8 * i) * C + c0 + tx];
  __syncthreads();
#pragma unroll
  for (int i = 0; i < 4; i++)
    dst[(size_t)(c0 + ty + 8 * i) * R + r0 + tx] = f2b(t[tx][ty + 8 * i]);
}

// same, 3 sources fused (Wq|Wk|Wv -> one [3072][1024] dst), z = source id
__global__ __launch_bounds__(256) void transpose_w3(
    const float* __restrict__ s0, const float* __restrict__ s1,
    const float* __restrict__ s2, uint16_t* __restrict__ dst) {
  __shared__ float t[32][33];
  const float* src = blockIdx.z == 0 ? s0 : (blockIdx.z == 1 ? s1 : s2);
  uint16_t* d = dst + (size_t)blockIdx.z * 1024 * 1024;
  int c0 = blockIdx.x * 32, r0 = blockIdx.y * 32;
  int tx = threadIdx.x & 31, ty = threadIdx.x >> 5;
#pragma unroll
  for (int i = 0; i < 4; i++)
    t[ty + 8 * i][tx] = src[(size_t)(r0 + ty + 8 * i) * 1024 + c0 + tx];
  __syncthreads();
#pragma unroll
  for (int i = 0; i < 4; i++)
    d[(size_t)(c0 + ty + 8 * i) * 1024 + r0 + tx] = f2b(t[tx][ty + 8 * i]);
}

// ------------------------------------- V transpose: qkv[t][2048+h*64+d] -> Vt[bh][d][s]
__global__ __launch_bounds__(256) void transpose_v(
    const uint16_t* __restrict__ qkv, uint16_t* __restrict__ Vt) {
  __shared__ uint16_t t[32][33];
  int bh = blockIdx.z, b = bh >> 4, h = bh & 15;
  int s0 = blockIdx.x * 32, d0 = blockIdx.y * 32;
  int tx = threadIdx.x & 31, ty = threadIdx.x >> 5;
#pragma unroll
  for (int i = 0; i < 4; i++)
    t[ty + 8 * i][tx] =
        qkv[(size_t)(b * 2048 + s0 + ty + 8 * i) * 3072 + 2048 + h * 64 + d0 + tx];
  __syncthreads();
#pragma unroll
  for (int i = 0; i < 4; i++)
    Vt[((size_t)bh * 64 + d0 + ty + 8 * i) * 2048 + s0 + tx] = t[tx][ty + 8 * i];
}

// -------------------------------------------------------------- bias concat [bq|bk|bv]
__global__ __launch_bounds__(256) void concat3(
    const float* __restrict__ a, const float* __restrict__ b,
    const float* __restrict__ c, float* __restrict__ o) {
  int i = blockIdx.x * 256 + threadIdx.x;
  o[i] = i < 1024 ? a[i] : (i < 2048 ? b[i - 1024] : c[i - 2048]);
}

// ------------------------------------------------------------------------- GEMM
// 128x128 tile, 4 waves, BK=32 linear / BK=64 swizzled, 2-phase pipeline.
// NSPLIT=2: K halved across blocks; ln_res sums partials.
template <int MODE, int NSPLIT, int BK>
__global__ __launch_bounds__(256) void gemm_bt(
    const uint16_t* __restrict__ A, const uint16_t* __restrict__ Bt,
    const float* __restrict__ bias, void* __restrict__ Cv, void* __restrict__ Cv2,
    int M, int N, int K, int nx) {
  __shared__ uint16_t As[2][128 * BK];
  __shared__ uint16_t Bs[2][128 * BK];
  int nwg = gridDim.x, bid = blockIdx.x;
  int cpx = nwg >> 3;
  int swzb = (bid & 7) * cpx + (bid >> 3);  // XCD (bid&7) owns contiguous chunk
  int ntile = nwg / NSPLIT;
  int sp = swzb / ntile, r = swzb % ntile;
  int n0 = (r % nx) * 128, m0 = (r / nx) * 128;
  int Klen = K / NSPLIT;
  int tid = threadIdx.x, w = tid >> 6, l = tid & 63;
  int wr = w >> 1, wc = w & 1;
  int lr = l & 15, lg = l >> 4, lk8 = lg * 8;
  f32x4 acc[4][4] = {};
  const uint16_t* Ab = A + (size_t)m0 * K + sp * Klen;
  const uint16_t* Bb = Bt + (size_t)n0 * K + sp * Klen;

  auto stage = [&](int buf, int k0) {
    if (BK == 32) {
#pragma unroll
      for (int i = 0; i < 2; i++) {
        int c = 2 * w + i;             // 8 chunks of 16 rows
        int rr = c * 16 + (l >> 2);
        gload_lds16(Ab + (size_t)rr * K + k0 + (l & 3) * 8, &As[buf][c * 512]);
        gload_lds16(Bb + (size_t)rr * K + k0 + (l & 3) * 8, &Bs[buf][c * 512]);
      }
    } else {
      int colb = (((l & 7) ^ ((l >> 3) & 7)) << 4);  // inverse-swizzled source
#pragma unroll
      for (int i = 0; i < 4; i++) {
        int c = 4 * w + i;             // 16 chunks of 8 rows
        int rr = c * 8 + (l >> 3);
        gload_lds16((const uint8_t*)(Ab + (size_t)rr * K + k0) + colb,
                    &As[buf][c * 512]);
        gload_lds16((const uint8_t*)(Bb + (size_t)rr * K + k0) + colb,
                    &Bs[buf][c * 512]);
      }
    }
  };

  stage(0, 0);
  __syncthreads();

  for (int k0 = 0; k0 < Klen; k0 += BK) {
    int cur = (k0 / BK) & 1;
    if (k0 + BK < Klen) stage(cur ^ 1, k0 + BK);  // prefetch next tile
    if (BK == 32) {
      bf16x8 af[4], bf[4];
#pragma unroll
      for (int m = 0; m < 4; m++)
        af[m] = *(const bf16x8*)&As[cur][(wr * 64 + m * 16 + lr) * 32 + lk8];
#pragma unroll
      for (int n = 0; n < 4; n++)
        bf[n] = *(const bf16x8*)&Bs[cur][(wc * 64 + n * 16 + lr) * 32 + lk8];
#pragma unroll
      for (int m = 0; m < 4; m++)
#pragma unroll
        for (int n = 0; n < 4; n++)
          acc[m][n] = __builtin_amdgcn_mfma_f32_16x16x32_bf16(af[m], bf[n], acc[m][n], 0, 0, 0);
    } else {
      int sw = (lr & 7) << 4;
#pragma unroll
      for (int ks = 0; ks < 2; ks++) {
        int off = ((ks << 6) | (lg << 4)) ^ sw;  // swizzled read (matches source)
        bf16x8 af[4], bf[4];
#pragma unroll
        for (int m = 0; m < 4; m++)
          af[m] = *(const bf16x8*)((const uint8_t*)&As[cur][(wr * 64 + m * 16 + lr) * 64] + off);
#pragma unroll
        for (int n = 0; n < 4; n++)
          bf[n] = *(const bf16x8*)((const uint8_t*)&Bs[cur][(wc * 64 + n * 16 + lr) * 64] + off);
#pragma unroll
        for (int m = 0; m < 4; m++)
#pragma unroll
          for (int n = 0; n < 4; n++)
            acc[m][n] = __builtin_amdgcn_mfma_f32_16x16x32_bf16(af[m], bf[n], acc[m][n], 0, 0, 0);
      }
    }
    __syncthreads();  // drains prefetch vmcnt + all waves done with cur
  }

  void* dstv = (NSPLIT == 1 || sp == 0) ? Cv : Cv2;
  int g4 = lg * 4;
#pragma unroll
  for (int m = 0; m < 4; m++) {
    int row = m0 + wr * 64 + m * 16 + g4;
#pragma unroll
    for (int n = 0; n < 4; n++) {
      int col = n0 + wc * 64 + n * 16 + lr;
      float bv = (NSPLIT == 1 || sp == 0) ? bias[col] : 0.f;
#pragma unroll
      for (int j = 0; j < 4; j++) {
        float v = acc[m][n][j] + bv;
        if (MODE == 2) v = fmaxf(v, 0.f);
        size_t idx = (size_t)(row + j) * N + col;
        if (MODE == 0) ((float*)dstv)[idx] = v;
        else           ((uint16_t*)dstv)[idx] = f2b(v);
      }
    }
  }
}

// ---------------------------------------------------- GEMM 256x256, phase-split
// (unchanged from round 12 — see notes there)
template <int MODE>
__global__ __launch_bounds__(512, 2) void gemm256(
    const uint16_t* __restrict__ A, const uint16_t* __restrict__ Bt,
    const float* __restrict__ bias, void* __restrict__ Cv,
    int M, int N, int K, int nx) {
  __shared__ uint16_t As[2][256 * 64];
  __shared__ uint16_t Bs[2][256 * 64];
  int nwg = gridDim.x, bid = blockIdx.x;
  int cpx = nwg >> 3;
  int swzb = (bid & 7) * cpx + (bid >> 3);
  int n0 = (swzb % nx) * 256, m0 = (swzb / nx) * 256;
  int tid = threadIdx.x, w = tid >> 6, l = tid & 63;
  int wr = w >> 2, wc = w & 3;
  int lr = l & 15, lg = l >> 4;
  f32x4 acc[8][4] = {};
  const uint16_t* Ab = A + (size_t)m0 * K;
  const uint16_t* Bb = Bt + (size_t)n0 * K;
  int colb = (((l & 7) ^ (l >> 3)) << 4);  // inverse-swizzled source col
  int srl = l >> 3;                        // lane sub-row 0..7

  auto stageH = [&](int buf, int k0, int h) {
    const uint16_t* base = (h < 2) ? Ab : Bb;
    uint16_t* lds = (h < 2) ? &As[buf][0] : &Bs[buf][0];
    int hh = (h & 1) * 128;
#pragma unroll
    for (int j = 0; j < 2; j++) {
      int rr = hh + j * 64 + w * 8;  // wave-uniform row base
      gload_lds16((const uint8_t*)(base + (size_t)(rr + srl) * K + k0) + colb,
                  &lds[rr * 64]);
    }
  };

#pragma unroll
  for (int h = 0; h < 4; h++) stageH(0, 0, h);
  asm volatile("s_waitcnt vmcnt(0)" ::: "memory");
  __builtin_amdgcn_s_barrier();

  int nt = K >> 6;
  int swr = (lr & 7) << 4;
  for (int t = 0; t < nt; t++) {
    int buf = t & 1;
    bf16x8 bfr[2][4];
#pragma unroll
    for (int ks = 0; ks < 2; ks++) {
#pragma unroll
      for (int mq = 0; mq < 2; mq++) {
        const int ph = ks * 2 + mq;
        int off = ((ks << 6) | (lg << 4)) ^ swr;
        bf16x8 af[4];
#pragma unroll
        for (int m = 0; m < 4; m++) {
          int row = wr * 128 + (mq * 4 + m) * 16 + lr;
          af[m] = *(const bf16x8*)((const uint8_t*)&As[buf][row * 64] + off);
        }
        if (mq == 0) {
#pragma unroll
          for (int n = 0; n < 4; n++) {
            int row = wc * 64 + n * 16 + lr;
            bfr[ks][n] = *(const bf16x8*)((const uint8_t*)&Bs[buf][row * 64] + off);
          }
        }
        if (t + 1 < nt) {
          if (ph == 0) { stageH(buf ^ 1, (t + 1) * 64, 0); stageH(buf ^ 1, (t + 1) * 64, 1); }
          if (ph == 1) { stageH(buf ^ 1, (t + 1) * 64, 2); stageH(buf ^ 1, (t + 1) * 64, 3); }
        }
        __builtin_amdgcn_s_barrier();
        asm volatile("s_waitcnt lgkmcnt(0)" ::: "memory");
        __builtin_amdgcn_sched_barrier(0);
        __builtin_amdgcn_s_setprio(1);
#pragma unroll
        for (int m = 0; m < 4; m++)
#pragma unroll
          for (int n = 0; n < 4; n++)
            acc[mq * 4 + m][n] = __builtin_amdgcn_mfma_f32_16x16x32_bf16(
                af[m], bfr[ks][n], acc[mq * 4 + m][n], 0, 0, 0);
        __builtin_amdgcn_s_setprio(0);
        if (ph == 3) asm volatile("s_waitcnt vmcnt(0)" ::: "memory");  // t+1 loads done
        __builtin_amdgcn_s_barrier();
      }
    }
  }

#pragma unroll
  for (int m = 0; m < 8; m++) {
    int row = m0 + wr * 128 + m * 16 + lg * 4;
#pragma unroll
    for (int n = 0; n < 4; n++) {
      int col = n0 + wc * 64 + n * 16 + lr;
      float bv = bias[col];
#pragma unroll
      for (int j = 0; j < 4; j++) {
        float v = acc[m][n][j] + bv;
        if (MODE == 2) v = fmaxf(v, 0.f);
        size_t idx = (size_t)(row + j) * N + col;
        if (MODE == 0) ((float*)Cv)[idx] = v;
        else           ((uint16_t*)Cv)[idx] = f2b(v);
      }
    }
  }
}

// --------------------------------------------------------------- fused attention
// 32x32x16 MFMA rebuild: 512 blocks, 4 waves, wave owns 32 q rows in ONE
// 32-col fragment (q = lane&31). Swapped QK^T: S^T[key][q] 32x32 tile; lane
// holds 16 keys (row=(reg&3)+8*(reg>>2)+4*(lane>>5), m74/m101-verified).
// P stays IN REGISTERS: exp2 -> cvt_pk pairs -> 8x shfl_xor(32) + half-lane
// selects build PV's B-fragments directly (keys are lane-local) -> no P-LDS
// round trip, no wave_barriers, denominator = 1 shfl at end. KVBLK=128
// double-buffered via global_load_lds, XOR-swizzled. NO-MAX softmax (bounded
// scores), scale folded into Q. LDS 64 KB -> 2 blocks/CU.
__global__ __launch_bounds__(256, 2) void attn_fused(
    const uint16_t* __restrict__ qkv, const uint16_t* __restrict__ Vt,
    uint16_t* __restrict__ outb) {
  constexpr int LQ = 3072;
  constexpr float SC = 0.18033688f;  // 0.125 * log2(e)
  int L = blockIdx.x;
  int qb = (L >> 3) & 15;
  int bh = (L & 7) + 8 * (L >> 7);
  int b = bh >> 4, h = bh & 15;
  int w = threadIdx.x >> 6, l = threadIdx.x & 63;
  int l31 = l & 31, lh = l >> 5;
  int qbase = qb * 128 + w * 32;

  __shared__ uint16_t Kbuf[2][2][64 * 64];  // [dbuf][sub][key-row][d]
  __shared__ uint16_t Vbuf[2][2][64 * 64];  // [dbuf][sub][d-row][key]

  // Q (B-operand): lane holds Q[q=qbase+l31][d = j*16 + lh*8 + 0..7], prescaled
  const uint16_t* qrow = qkv + (size_t)(b * 2048 + qbase + l31) * LQ + h * 64;
  bf16x8 qf[4];
#pragma unroll
  for (int j = 0; j < 4; j++)
    qf[j] = scale8(*(const bf16x8*)(qrow + j * 16 + lh * 8), SC);

  float rs = 0.f;
  f32x16 acc0 = {}, acc1 = {};  // O^T d-blocks 0/1; col=q=l31

  const uint8_t* kq = (const uint8_t*)qkv;
  const uint8_t* vq = (const uint8_t*)Vt;
  int colb = (((l & 7) ^ ((l >> 3) & 7)) << 4);
  int Rl = w * 16 + (l >> 3);

  auto stageKV = [&](int buf, int kb) {
#pragma unroll
    for (int s2 = 0; s2 < 2; s2++) {
#pragma unroll
      for (int c2 = 0; c2 < 2; c2++) {
        int R = Rl + c2 * 8;
        const uint8_t* ks =
            kq + ((size_t)(b * 2048 + kb + s2 * 64 + R) * LQ + 1024 + h * 64) * 2 + colb;
        gload_lds16(ks, &Kbuf[buf][s2][(w * 16 + c2 * 8) * 64]);
        const uint8_t* vs =
            vq + ((size_t)(bh * 64 + R) * 2048 + kb + s2 * 64) * 2 + colb;
        gload_lds16(vs, &Vbuf[buf][s2][(w * 16 + c2 * 8) * 64]);
      }
    }
  };

  stageKV(0, 0);
  __syncthreads();

  bool lo = (lh == 0);
  for (int kb = 0; kb < 2048; kb += 128) {
    int cur = (kb >> 7) & 1;
    if (kb + 128 < 2048) stageKV(cur ^ 1, kb + 128);

#pragma unroll
    for (int t32 = 0; t32 < 4; t32++) {
      int s2 = t32 >> 1;
      int ko = (t32 & 1) * 32;  // key offset within 64-key sub-tile
      const uint8_t* Kb = (const uint8_t*)Kbuf[cur][s2];
      const uint8_t* Vb = (const uint8_t*)Vbuf[cur][s2];
      // QK: S^T[key][q]. A=K: row=key=ko+l31, k(d) = j*16 + lh*8 + e
      int krow = ko + l31;
      const uint8_t* krb = Kb + krow * 128;
      int ksw = (krow & 7) << 4;
      f32x16 s = {};
      __builtin_amdgcn_s_setprio(1);
#pragma unroll
      for (int j = 0; j < 4; j++) {
        bf16x8 kf = *(const bf16x8*)(krb + ((j * 32 + lh * 16) ^ ksw));
        s = __builtin_amdgcn_mfma_f32_32x32x16_bf16(kf, qf[j], s, 0, 0, 0);
      }
      __builtin_amdgcn_s_setprio(0);
      // p = exp2(s); lane key(reg) = ko + (reg&3) + 8*(reg>>2) + 4*lh
      float p[16];
#pragma unroll
      for (int r = 0; r < 16; r++) p[r] = __builtin_amdgcn_exp2f(s[r]);
#pragma unroll
      for (int r = 0; r < 16; r += 4) rs += (p[r] + p[r + 1]) + (p[r + 2] + p[r + 3]);
      // pack pairs: wv[i] = keys (lo: {2i,2i+1 of pattern} | hi: +4)
      uint32_t wv[8], sv[8];
#pragma unroll
      for (int i = 0; i < 8; i++) wv[i] = pkbf2(p[2 * i], p[2 * i + 1]);
#pragma unroll
      for (int i = 0; i < 8; i++) sv[i] = __shfl_xor(wv[i], 32);
      // B-fragments (col=q, k=key): B1 = keys ko+0..15, B2 = keys ko+16..31
      union { uint32_t u[4]; bf16x8 v; } B1, B2;
      B1.u[0] = lo ? wv[0] : sv[2];
      B1.u[1] = lo ? wv[1] : sv[3];
      B1.u[2] = lo ? sv[0] : wv[2];
      B1.u[3] = lo ? sv[1] : wv[3];
      B2.u[0] = lo ? wv[4] : sv[6];
      B2.u[1] = lo ? wv[5] : sv[7];
      B2.u[2] = lo ? sv[4] : wv[6];
      B2.u[3] = lo ? sv[5] : wv[7];
      // PV: A=V^T: row=d=dblk*32+l31, k(key) = ko + kc*16 + lh*8 + e
      int vsw = (l31 & 7) << 4;
      const uint8_t* vrb0 = Vb + l31 * 128;
      const uint8_t* vrb1 = Vb + (32 + l31) * 128;
      __builtin_amdgcn_s_setprio(1);
      {
        bf16x8 v00 = *(const bf16x8*)(vrb0 + ((ko * 2 + lh * 16) ^ vsw));
        bf16x8 v01 = *(const bf16x8*)(vrb0 + ((ko * 2 + 32 + lh * 16) ^ vsw));
        acc0 = __builtin_amdgcn_mfma_f32_32x32x16_bf16(v00, B1.v, acc0, 0, 0, 0);
        acc0 = __builtin_amdgcn_mfma_f32_32x32x16_bf16(v01, B2.v, acc0, 0, 0, 0);
        bf16x8 v10 = *(const bf16x8*)(vrb1 + ((ko * 2 + lh * 16) ^ vsw));
        bf16x8 v11 = *(const bf16x8*)(vrb1 + ((ko * 2 + 32 + lh * 16) ^ vsw));
        acc1 = __builtin_amdgcn_mfma_f32_32x32x16_bf16(v10, B1.v, acc1, 0, 0, 0);
        acc1 = __builtin_amdgcn_mfma_f32_32x32x16_bf16(v11, B2.v, acc1, 0, 0, 0);
      }
      __builtin_amdgcn_s_setprio(0);
    }
    __syncthreads();  // drains stage vmcnt + all waves done reading cur
  }
  // denominator: lanes l and l^32 share q
  rs += __shfl_xor(rs, 32);
  float inv = 1.f / rs;
  // write O[q][d]: acc reg rg -> d = dblk*32 + (rg>>2)*8 + 4*lh + (rg&3)
  uint16_t* orow = outb + (size_t)(b * 2048 + qbase + l31) * 1024 + h * 64;
#pragma unroll
  for (int dblk = 0; dblk < 2; dblk++) {
    const f32x16& a = dblk ? acc1 : acc0;
#pragma unroll
    for (int g = 0; g < 4; g++) {
      int d0 = dblk * 32 + g * 8 + 4 * lh;
      uint2 r;
      r.x = pkbf2(a[4 * g] * inv, a[4 * g + 1] * inv);
      r.y = pkbf2(a[4 * g + 2] * inv, a[4 * g + 3] * inv);
      *(uint2*)(orow + d0) = r;
    }
  }
}

// ----------------------------------------------------- LayerNorm(x + r0 [+ r1])
// XBF: xr is bf16 (residual trunk carried in bf16 to halve LN traffic)
template <int XBF, int WF32, int WB16, int NR>
__global__ __launch_bounds__(256) void ln_res(
    const void* __restrict__ xr, const float* __restrict__ r0,
    const float* __restrict__ r1, const float* __restrict__ gam,
    const float* __restrict__ bet, float* __restrict__ of32,
    uint16_t* __restrict__ ob16) {
  int row = blockIdx.x, t = threadIdx.x;
  int w = t >> 6, l = t & 63;
  float v0, v1, v2, v3;
  if (XBF) {
    uint2 u = ((const uint2*)((const uint16_t*)xr + (size_t)row * 1024))[t];
    v0 = __uint_as_float((u.x & 0xffffu) << 16);
    v1 = __uint_as_float(u.x & 0xffff0000u);
    v2 = __uint_as_float((u.y & 0xffffu) << 16);
    v3 = __uint_as_float(u.y & 0xffff0000u);
  } else {
    float4 xv = ((const float4*)((const float*)xr + (size_t)row * 1024))[t];
    v0 = xv.x; v1 = xv.y; v2 = xv.z; v3 = xv.w;
  }
  float4 rv = ((const float4*)(r0 + (size_t)row * 1024))[t];
  v0 += rv.x; v1 += rv.y; v2 += rv.z; v3 += rv.w;
  if (NR == 2) {
    float4 r2 = ((const float4*)(r1 + (size_t)row * 1024))[t];
    v0 += r2.x; v1 += r2.y; v2 += r2.z; v3 += r2.w;
  }
  float s = v0 + v1 + v2 + v3;
  float sq = v0 * v0 + v1 * v1 + v2 * v2 + v3 * v3;
#pragma unroll
  for (int d = 1; d < 64; d <<= 1) {
    s += __shfl_xor(s, d);
    sq += __shfl_xor(sq, d);
  }
  __shared__ float red[8];
  if (l == 0) { red[w] = s; red[4 + w] = sq; }
  __syncthreads();
  s = red[0] + red[1] + red[2] + red[3];
  sq = red[4] + red[5] + red[6] + red[7];
  float mean = s * (1.f / 1024.f);
  float var = sq * (1.f / 1024.f) - mean * mean;
  float rstd = rsqrtf(var + 1e-5f);
  float4 gv = ((const float4*)gam)[t];
  float4 bv = ((const float4*)bet)[t];
  float y0 = (v0 - mean) * rstd * gv.x + bv.x;
  float y1 = (v1 - mean) * rstd * gv.y + bv.y;
  float y2 = (v2 - mean) * rstd * gv.z + bv.z;
  float y3 = (v3 - mean) * rstd * gv.w + bv.w;
  if (WF32) {
    float4 yv; yv.x = y0; yv.y = y1; yv.z = y2; yv.w = y3;
    ((float4*)(of32 + (size_t)row * 1024))[t] = yv;
  }
  if (WB16) {
    uint2 r;
    r.x = pkbf2(y0, y1);
    r.y = pkbf2(y2, y3);
    ((uint2*)(ob16 + (size_t)row * 1024))[t] = r;
  }
}

// ---------------------------------------------------------------- workspace map
static constexpr size_t OFF_XB    = 0;                          // 8 MB x_bf16; reused: attn_out
static constexpr size_t OFF_WQKVT = (size_t)8 << 20;            // 6 MB [3072][1024]
static constexpr size_t OFF_WOT   = (size_t)14 << 20;           // 2 MB [1024][1024]
static constexpr size_t OFF_W1T   = (size_t)16 << 20;           // 8 MB [4096][1024]
static constexpr size_t OFF_W2T   = (size_t)24 << 20;           // 8 MB [1024][4096]
static constexpr size_t OFF_BIAS  = (size_t)32 << 20;           // 12 KB f32 (pad 64K)
static constexpr size_t OFF_QKV   = OFF_BIAS + ((size_t)64 << 10);  // 24 MB; +VT reused: H (32MB)
static constexpr size_t OFF_VT    = OFF_QKV + ((size_t)24 << 20);   // 8 MB [32][64][2048]
static constexpr size_t OFF_PROJ  = OFF_VT + ((size_t)8 << 20);     // 16 MB f32 (split-K partial 0)
static constexpr size_t OFF_LN1B  = OFF_PROJ + ((size_t)16 << 20);  // 8 MB bf16 trunk
static constexpr size_t OFF_PROJ2 = OFF_LN1B + ((size_t)8 << 20);   // 16 MB f32 (split-K partial 1)
// total ~104 MB

extern "C" void kernel_launch(void* const* d_in, const int* in_sizes, int n_in,
                              void* d_out, int out_size, void* d_ws, size_t ws_size,
                              hipStream_t stream) {
  const float* x   = (const float*)d_in[0];
  const float* Wq  = (const float*)d_in[1];
  const float* bq  = (const float*)d_in[2];
  const float* Wk  = (const float*)d_in[3];
  const float* bk  = (const float*)d_in[4];
  const float* Wv  = (const float*)d_in[5];
  const float* bv  = (const float*)d_in[6];
  const float* Wo  = (const float*)d_in[7];
  const float* bo  = (const float*)d_in[8];
  const float* W1  = (const float*)d_in[9];
  const float* b1  = (const float*)d_in[10];
  const float* W2  = (const float*)d_in[11];
  const float* b2  = (const float*)d_in[12];
  const float* g1  = (const float*)d_in[13];
  const float* be1 = (const float*)d_in[14];
  const float* g2  = (const float*)d_in[15];
  const float* be2 = (const float*)d_in[16];
  float* out = (float*)d_out;
  uint8_t* ws = (uint8_t*)d_ws;

  uint16_t* xb    = (uint16_t*)(ws + OFF_XB);
  uint16_t* wqkt  = (uint16_t*)(ws + OFF_WQKVT);
  uint16_t* wot   = (uint16_t*)(ws + OFF_WOT);
  uint16_t* w1t   = (uint16_t*)(ws + OFF_W1T);
  uint16_t* w2t   = (uint16_t*)(ws + OFF_W2T);
  float*    bqkv  = (float*)(ws + OFF_BIAS);
  uint16_t* qkvb  = (uint16_t*)(ws + OFF_QKV);
  uint16_t* vt    = (uint16_t*)(ws + OFF_VT);
  float*    proj  = (float*)(ws + OFF_PROJ);
  float*    proj2 = (float*)(ws + OFF_PROJ2);
  uint16_t* ln1b  = (uint16_t*)(ws + OFF_LN1B);
  uint16_t* attnb = (uint16_t*)(ws + OFF_XB);   // alias: xb dead after QKV gemm
  uint16_t* hbuf  = (uint16_t*)(ws + OFF_QKV);  // alias: qkv+vt dead after attention

  // 1. cast x to bf16
  cast_bf16_kernel<<<4096, 256, 0, stream>>>(x, xb, 4096 * 1024 / 4);
  // 2. transpose weights to bf16 [N][K]
  transpose_w3<<<dim3(32, 32, 3), 256, 0, stream>>>(Wq, Wk, Wv, wqkt);
  transpose_w<<<dim3(32, 32), 256, 0, stream>>>(Wo, wot, 1024, 1024);
  transpose_w<<<dim3(128, 32), 256, 0, stream>>>(W1, w1t, 1024, 4096);
  transpose_w<<<dim3(32, 128), 256, 0, stream>>>(W2, w2t, 4096, 1024);
  concat3<<<12, 256, 0, stream>>>(bq, bk, bv, bqkv);
  // 3. fused QKV projection (BK=64 swizzled): [4096,1024] x [1024,3072] -> bf16
  gemm_bt<1, 1, 64><<<768, 256, 0, stream>>>(xb, wqkt, bqkv, qkvb, nullptr,
                                             4096, 3072, 1024, 24);
  // 4. V transpose per head
  transpose_v<<<dim3(64, 2, 32), 256, 0, stream>>>(qkvb, vt);
  // 5. fused attention (512 blocks, 32x32 MFMA, in-register P)
  attn_fused<<<512, 256, 0, stream>>>(qkvb, vt, attnb);
  // 6. output projection, split-K x2, BK=64 -> fp32 partials
  gemm_bt<0, 2, 64><<<512, 256, 0, stream>>>(attnb, wot, bo, proj, proj2,
                                             4096, 1024, 1024, 8);
  // 7. LN1(x + proj + proj2) -> bf16 trunk only
  ln_res<0, 0, 1, 2><<<4096, 256, 0, stream>>>(x, proj, proj2, g1, be1,
                                               nullptr, ln1b);
  // 8. MLP1 + relu -> bf16, 256x256 phase-split schedule (256 blocks, 1/CU)
  gemm256<2><<<256, 512, 0, stream>>>(ln1b, w1t, b1, hbuf, 4096, 4096, 1024, 16);
  // 9. MLP2, split-K x2, BK=64 -> fp32 partials
  gemm_bt<0, 2, 64><<<512, 256, 0, stream>>>(hbuf, w2t, b2, proj, proj2,
                                             4096, 1024, 4096, 8);
  // 10. LN2(ln1b + proj + proj2) -> d_out fp32
  ln_res<1, 1, 0, 2><<<4096, 256, 0, stream>>>(ln1b, proj, proj2, g2, be2,
                                               out, nullptr);
}

// Round 14
// 217.737 us; speedup vs baseline: 1.0941x; 1.0941x over previous
//
#include <hip/hip_runtime.h>
#include <hip/hip_bf16.h>
#include <cstdint>

#define DEV __device__ __forceinline__

typedef __attribute__((ext_vector_type(8))) __bf16 bf16x8;
typedef __attribute__((ext_vector_type(4))) float f32x4;

// fp32 -> bf16 via HW cvt (single v_cvt instruction)
DEV uint16_t f2b(float f) {
  __hip_bfloat16 h = __float2bfloat16(f);
  return *(uint16_t*)&h;
}
// pack two floats into a bf16x2 word
DEV uint32_t pkbf2(float a, float b) {
  return (uint32_t)f2b(a) | ((uint32_t)f2b(b) << 16);
}

// async global->LDS, 16B per lane. LDS base must be wave-uniform; HW writes
// base + lane*16. Global source address is per-lane.
DEV void gload_lds16(const void* g, void* l) {
  __builtin_amdgcn_global_load_lds(
      (const __attribute__((address_space(1))) void*)g,
      (__attribute__((address_space(3))) void*)l, 16, 0, 0);
}

// scale a bf16x8 by a constant (via fp32, RNE back to bf16)
DEV bf16x8 scale8(bf16x8 v, float sc) {
  union { bf16x8 b; uint16_t u[8]; } in, out;
  in.b = v;
#pragma unroll
  for (int i = 0; i < 8; i++) {
    float x = __uint_as_float(((uint32_t)in.u[i]) << 16);
    out.u[i] = f2b(x * sc);
  }
  return out.b;
}

// ---------------------------------------------------------------- cast x -> bf16
__global__ __launch_bounds__(256) void cast_bf16_kernel(
    const float* __restrict__ src, uint16_t* __restrict__ dst, int n4) {
  int i = blockIdx.x * 256 + threadIdx.x;
  if (i < n4) {
    float4 v = ((const float4*)src)[i];
    uint2 r;
    r.x = pkbf2(v.x, v.y);
    r.y = pkbf2(v.z, v.w);
    ((uint2*)dst)[i] = r;
  }
}

// ------------------------------------------- weight transpose fp32[R][C] -> bf16[C][R]
__global__ __launch_bounds__(256) void transpose_w(
    const float* __restrict__ src, uint16_t* __restrict__ dst, int R, int C) {
  __shared__ float t[32][33];
  int c0 = blockIdx.x * 32, r0 = blockIdx.y * 32;
  int tx = threadIdx.x & 31, ty = threadIdx.x >> 5;  // 32 x 8
#pragma unroll
  for (int i = 0; i < 4; i++)
    t[ty + 8 * i][tx] = src[(size_t)(r0 + ty + 8 * i) * C + c0 + tx];
  __syncthreads();
#pragma unroll
  for (int i = 0; i < 4; i++)
    dst[(size_t)(c0 + ty + 8 * i) * R + r0 + tx] = f2b(t[tx][ty + 8 * i]);
}

// same, 3 sources fused (Wq|Wk|Wv -> one [3072][1024] dst), z = source id
__global__ __launch_bounds__(256) void transpose_w3(
    const float* __restrict__ s0, const float* __restrict__ s1,
    const float* __restrict__ s2, uint16_t* __restrict__ dst) {
  __shared__ float t[32][33];
  const float* src = blockIdx.z == 0 ? s0 : (blockIdx.z == 1 ? s1 : s2);
  uint16_t* d = dst + (size_t)blockIdx.z * 1024 * 1024;
  int c0 = blockIdx.x * 32, r0 = blockIdx.y * 32;
  int tx = threadIdx.x & 31, ty = threadIdx.x >> 5;
#pragma unroll
  for (int i = 0; i < 4; i++)
    t[ty + 8 * i][tx] = src[(size_t)(r0 + ty + 8 * i) * 1024 + c0 + tx];
  __syncthreads();
#pragma unroll
  for (int i = 0; i < 4; i++)
    d[(size_t)(c0 + ty + 8 * i) * 1024 + r0 + tx] = f2b(t[tx][ty + 8 * i]);
}

// ------------------------------------- V transpose: qkv[t][2048+h*64+d] -> Vt[bh][d][s]
__global__ __launch_bounds__(256) void transpose_v(
    const uint16_t* __restrict__ qkv, uint16_t* __restrict__ Vt) {
  __shared__ uint16_t t[32][33];
  int bh = blockIdx.z, b = bh >> 4, h = bh & 15;
  int s0 = blockIdx.x * 32, d0 = blockIdx.y * 32;
  int tx = threadIdx.x & 31, ty = threadIdx.x >> 5;
#pragma unroll
  for (int i = 0; i < 4; i++)
    t[ty + 8 * i][tx] =
        qkv[(size_t)(b * 2048 + s0 + ty + 8 * i) * 3072 + 2048 + h * 64 + d0 + tx];
  __syncthreads();
#pragma unroll
  for (int i = 0; i < 4; i++)
    Vt[((size_t)bh * 64 + d0 + ty + 8 * i) * 2048 + s0 + tx] = t[tx][ty + 8 * i];
}

// -------------------------------------------------------------- bias concat [bq|bk|bv]
__global__ __launch_bounds__(256) void concat3(
    const float* __restrict__ a, const float* __restrict__ b,
    const float* __restrict__ c, float* __restrict__ o) {
  int i = blockIdx.x * 256 + threadIdx.x;
  o[i] = i < 1024 ? a[i] : (i < 2048 ? b[i - 1024] : c[i - 2048]);
}

// ------------------------------------------------------------------------- GEMM
// 128x128 tile, 4 waves, BK=32 linear / BK=64 swizzled, 2-phase pipeline.
// NSPLIT=2: K halved across blocks; split 0 -> Cv (+bias), split 1 -> Cv2;
// ln_res sums partials (bf16 partials when MODE=1).
// MODE: 0 = fp32 out, 1 = bf16 out, 2 = bf16 out + relu
template <int MODE, int NSPLIT, int BK>
__global__ __launch_bounds__(256) void gemm_bt(
    const uint16_t* __restrict__ A, const uint16_t* __restrict__ Bt,
    const float* __restrict__ bias, void* __restrict__ Cv, void* __restrict__ Cv2,
    int M, int N, int K, int nx) {
  __shared__ uint16_t As[2][128 * BK];
  __shared__ uint16_t Bs[2][128 * BK];
  int nwg = gridDim.x, bid = blockIdx.x;
  int cpx = nwg >> 3;
  int swzb = (bid & 7) * cpx + (bid >> 3);  // XCD (bid&7) owns contiguous chunk
  int ntile = nwg / NSPLIT;
  int sp = swzb / ntile, r = swzb % ntile;
  int n0 = (r % nx) * 128, m0 = (r / nx) * 128;
  int Klen = K / NSPLIT;
  int tid = threadIdx.x, w = tid >> 6, l = tid & 63;
  int wr = w >> 1, wc = w & 1;
  int lr = l & 15, lg = l >> 4, lk8 = lg * 8;
  f32x4 acc[4][4] = {};
  const uint16_t* Ab = A + (size_t)m0 * K + sp * Klen;
  const uint16_t* Bb = Bt + (size_t)n0 * K + sp * Klen;

  auto stage = [&](int buf, int k0) {
    if (BK == 32) {
#pragma unroll
      for (int i = 0; i < 2; i++) {
        int c = 2 * w + i;             // 8 chunks of 16 rows
        int rr = c * 16 + (l >> 2);
        gload_lds16(Ab + (size_t)rr * K + k0 + (l & 3) * 8, &As[buf][c * 512]);
        gload_lds16(Bb + (size_t)rr * K + k0 + (l & 3) * 8, &Bs[buf][c * 512]);
      }
    } else {
      int colb = (((l & 7) ^ ((l >> 3) & 7)) << 4);  // inverse-swizzled source
#pragma unroll
      for (int i = 0; i < 4; i++) {
        int c = 4 * w + i;             // 16 chunks of 8 rows
        int rr = c * 8 + (l >> 3);
        gload_lds16((const uint8_t*)(Ab + (size_t)rr * K + k0) + colb,
                    &As[buf][c * 512]);
        gload_lds16((const uint8_t*)(Bb + (size_t)rr * K + k0) + colb,
                    &Bs[buf][c * 512]);
      }
    }
  };

  stage(0, 0);
  __syncthreads();

  for (int k0 = 0; k0 < Klen; k0 += BK) {
    int cur = (k0 / BK) & 1;
    if (k0 + BK < Klen) stage(cur ^ 1, k0 + BK);  // prefetch next tile
    if (BK == 32) {
      bf16x8 af[4], bf[4];
#pragma unroll
      for (int m = 0; m < 4; m++)
        af[m] = *(const bf16x8*)&As[cur][(wr * 64 + m * 16 + lr) * 32 + lk8];
#pragma unroll
      for (int n = 0; n < 4; n++)
        bf[n] = *(const bf16x8*)&Bs[cur][(wc * 64 + n * 16 + lr) * 32 + lk8];
#pragma unroll
      for (int m = 0; m < 4; m++)
#pragma unroll
        for (int n = 0; n < 4; n++)
          acc[m][n] = __builtin_amdgcn_mfma_f32_16x16x32_bf16(af[m], bf[n], acc[m][n], 0, 0, 0);
    } else {
      int sw = (lr & 7) << 4;
#pragma unroll
      for (int ks = 0; ks < 2; ks++) {
        int off = ((ks << 6) | (lg << 4)) ^ sw;  // swizzled read (matches source)
        bf16x8 af[4], bf[4];
#pragma unroll
        for (int m = 0; m < 4; m++)
          af[m] = *(const bf16x8*)((const uint8_t*)&As[cur][(wr * 64 + m * 16 + lr) * 64] + off);
#pragma unroll
        for (int n = 0; n < 4; n++)
          bf[n] = *(const bf16x8*)((const uint8_t*)&Bs[cur][(wc * 64 + n * 16 + lr) * 64] + off);
#pragma unroll
        for (int m = 0; m < 4; m++)
#pragma unroll
          for (int n = 0; n < 4; n++)
            acc[m][n] = __builtin_amdgcn_mfma_f32_16x16x32_bf16(af[m], bf[n], acc[m][n], 0, 0, 0);
      }
    }
    __syncthreads();  // drains prefetch vmcnt + all waves done with cur
  }

  void* dstv = (NSPLIT == 1 || sp == 0) ? Cv : Cv2;
  int g4 = lg * 4;
#pragma unroll
  for (int m = 0; m < 4; m++) {
    int row = m0 + wr * 64 + m * 16 + g4;
#pragma unroll
    for (int n = 0; n < 4; n++) {
      int col = n0 + wc * 64 + n * 16 + lr;
      float bv = (NSPLIT == 1 || sp == 0) ? bias[col] : 0.f;
#pragma unroll
      for (int j = 0; j < 4; j++) {
        float v = acc[m][n][j] + bv;
        if (MODE == 2) v = fmaxf(v, 0.f);
        size_t idx = (size_t)(row + j) * N + col;
        if (MODE == 0) ((float*)dstv)[idx] = v;
        else           ((uint16_t*)dstv)[idx] = f2b(v);
      }
    }
  }
}

// ---------------------------------------------------- GEMM 256x256, phase-split
// (round-12 verified: 512 thr, 8 waves, BK=64, 4 phases/K-tile, counted drain)
template <int MODE>
__global__ __launch_bounds__(512, 2) void gemm256(
    const uint16_t* __restrict__ A, const uint16_t* __restrict__ Bt,
    const float* __restrict__ bias, void* __restrict__ Cv,
    int M, int N, int K, int nx) {
  __shared__ uint16_t As[2][256 * 64];
  __shared__ uint16_t Bs[2][256 * 64];
  int nwg = gridDim.x, bid = blockIdx.x;
  int cpx = nwg >> 3;
  int swzb = (bid & 7) * cpx + (bid >> 3);
  int n0 = (swzb % nx) * 256, m0 = (swzb / nx) * 256;
  int tid = threadIdx.x, w = tid >> 6, l = tid & 63;
  int wr = w >> 2, wc = w & 3;
  int lr = l & 15, lg = l >> 4;
  f32x4 acc[8][4] = {};
  const uint16_t* Ab = A + (size_t)m0 * K;
  const uint16_t* Bb = Bt + (size_t)n0 * K;
  int colb = (((l & 7) ^ (l >> 3)) << 4);  // inverse-swizzled source col
  int srl = l >> 3;                        // lane sub-row 0..7

  auto stageH = [&](int buf, int k0, int h) {
    const uint16_t* base = (h < 2) ? Ab : Bb;
    uint16_t* lds = (h < 2) ? &As[buf][0] : &Bs[buf][0];
    int hh = (h & 1) * 128;
#pragma unroll
    for (int j = 0; j < 2; j++) {
      int rr = hh + j * 64 + w * 8;  // wave-uniform row base
      gload_lds16((const uint8_t*)(base + (size_t)(rr + srl) * K + k0) + colb,
                  &lds[rr * 64]);
    }
  };

#pragma unroll
  for (int h = 0; h < 4; h++) stageH(0, 0, h);
  asm volatile("s_waitcnt vmcnt(0)" ::: "memory");
  __builtin_amdgcn_s_barrier();

  int nt = K >> 6;
  int swr = (lr & 7) << 4;
  for (int t = 0; t < nt; t++) {
    int buf = t & 1;
    bf16x8 bfr[2][4];
#pragma unroll
    for (int ks = 0; ks < 2; ks++) {
#pragma unroll
      for (int mq = 0; mq < 2; mq++) {
        const int ph = ks * 2 + mq;
        int off = ((ks << 6) | (lg << 4)) ^ swr;
        bf16x8 af[4];
#pragma unroll
        for (int m = 0; m < 4; m++) {
          int row = wr * 128 + (mq * 4 + m) * 16 + lr;
          af[m] = *(const bf16x8*)((const uint8_t*)&As[buf][row * 64] + off);
        }
        if (mq == 0) {
#pragma unroll
          for (int n = 0; n < 4; n++) {
            int row = wc * 64 + n * 16 + lr;
            bfr[ks][n] = *(const bf16x8*)((const uint8_t*)&Bs[buf][row * 64] + off);
          }
        }
        if (t + 1 < nt) {
          if (ph == 0) { stageH(buf ^ 1, (t + 1) * 64, 0); stageH(buf ^ 1, (t + 1) * 64, 1); }
          if (ph == 1) { stageH(buf ^ 1, (t + 1) * 64, 2); stageH(buf ^ 1, (t + 1) * 64, 3); }
        }
        __builtin_amdgcn_s_barrier();
        asm volatile("s_waitcnt lgkmcnt(0)" ::: "memory");
        __builtin_amdgcn_sched_barrier(0);
        __builtin_amdgcn_s_setprio(1);
#pragma unroll
        for (int m = 0; m < 4; m++)
#pragma unroll
          for (int n = 0; n < 4; n++)
            acc[mq * 4 + m][n] = __builtin_amdgcn_mfma_f32_16x16x32_bf16(
                af[m], bfr[ks][n], acc[mq * 4 + m][n], 0, 0, 0);
        __builtin_amdgcn_s_setprio(0);
        if (ph == 3) asm volatile("s_waitcnt vmcnt(0)" ::: "memory");  // t+1 loads done
        __builtin_amdgcn_s_barrier();
      }
    }
  }

#pragma unroll
  for (int m = 0; m < 8; m++) {
    int row = m0 + wr * 128 + m * 16 + lg * 4;
#pragma unroll
    for (int n = 0; n < 4; n++) {
      int col = n0 + wc * 64 + n * 16 + lr;
      float bv = bias[col];
#pragma unroll
      for (int j = 0; j < 4; j++) {
        float v = acc[m][n][j] + bv;
        if (MODE == 2) v = fmaxf(v, 0.f);
        size_t idx = (size_t)(row + j) * N + col;
        if (MODE == 0) ((float*)Cv)[idx] = v;
        else           ((uint16_t*)Cv)[idx] = f2b(v);
      }
    }
  }
}

// --------------------------------------------------------------- fused attention
// (round-11/12 proven version: 512 blocks, 4 waves, 2 Q-frags/wave, 16x16 MFMA,
// KVBLK=128 double-buffered, XOR-swizzle, no-max softmax, deferred denominator)
__global__ __launch_bounds__(256, 2) void attn_fused(
    const uint16_t* __restrict__ qkv, const uint16_t* __restrict__ Vt,
    uint16_t* __restrict__ outb) {
  constexpr int LQ = 3072;
  constexpr float SC = 0.18033688f;  // 0.125 * log2(e)
  int L = blockIdx.x;
  int qb = (L >> 3) & 15;
  int bh = (L & 7) + 8 * (L >> 7);
  int b = bh >> 4, h = bh & 15;
  int w = threadIdx.x >> 6, l = threadIdx.x & 63;
  int lr = l & 15, lg = l >> 4;
  int qbase = qb * 128 + w * 32;

  __shared__ uint16_t Kbuf[2][2][64 * 64];  // [dbuf][sub][key-row][d]
  __shared__ uint16_t Vbuf[2][2][64 * 64];  // [dbuf][sub][d-row][key]
  __shared__ uint16_t Plds[4][2][16 * 64];  // per-wave, per-qfrag P tiles
  uint16_t* PwA = &Plds[w][0][0];
  uint16_t* PwB = &Plds[w][1][0];

  const uint16_t* qrowA = qkv + (size_t)(b * 2048 + qbase + lr) * LQ + h * 64;
  const uint16_t* qrowB = qrowA + (size_t)16 * LQ;
  bf16x8 qA0 = scale8(*(const bf16x8*)(qrowA + lg * 8), SC);
  bf16x8 qA1 = scale8(*(const bf16x8*)(qrowA + 32 + lg * 8), SC);
  bf16x8 qB0 = scale8(*(const bf16x8*)(qrowB + lg * 8), SC);
  bf16x8 qB1 = scale8(*(const bf16x8*)(qrowB + 32 + lg * 8), SC);

  float rsA = 0.f, rsB = 0.f;
  f32x4 oA[4] = {}, oB[4] = {};

  const uint8_t* kq = (const uint8_t*)qkv;
  const uint8_t* vq = (const uint8_t*)Vt;
  int colb = (((l & 7) ^ ((l >> 3) & 7)) << 4);
  int Rl = w * 16 + (l >> 3);

  auto stageKV = [&](int buf, int kb) {
#pragma unroll
    for (int s2 = 0; s2 < 2; s2++) {
#pragma unroll
      for (int c2 = 0; c2 < 2; c2++) {
        int R = Rl + c2 * 8;
        const uint8_t* ks =
            kq + ((size_t)(b * 2048 + kb + s2 * 64 + R) * LQ + 1024 + h * 64) * 2 + colb;
        gload_lds16(ks, &Kbuf[buf][s2][(w * 16 + c2 * 8) * 64]);
        const uint8_t* vs =
            vq + ((size_t)(bh * 64 + R) * 2048 + kb + s2 * 64) * 2 + colb;
        gload_lds16(vs, &Vbuf[buf][s2][(w * 16 + c2 * 8) * 64]);
      }
    }
  };

  stageKV(0, 0);
  __syncthreads();

  int swz = (lr & 7) << 4;
  for (int kb = 0; kb < 2048; kb += 128) {
    int cur = (kb >> 7) & 1;
    if (kb + 128 < 2048) stageKV(cur ^ 1, kb + 128);

#pragma unroll
    for (int s2 = 0; s2 < 2; s2++) {
      const uint8_t* Kb = (const uint8_t*)Kbuf[cur][s2];
      const uint8_t* Vb = (const uint8_t*)Vbuf[cur][s2];
      f32x4 sA[4], sB[4];
      __builtin_amdgcn_s_setprio(1);
#pragma unroll
      for (int t = 0; t < 4; t++) {
        const uint8_t* rb = Kb + (16 * t + lr) * 128;
        bf16x8 k0 = *(const bf16x8*)(rb + ((lg << 4) ^ swz));
        bf16x8 k1 = *(const bf16x8*)(rb + ((64 | (lg << 4)) ^ swz));
        f32x4 zA = {};
        zA = __builtin_amdgcn_mfma_f32_16x16x32_bf16(k0, qA0, zA, 0, 0, 0);
        zA = __builtin_amdgcn_mfma_f32_16x16x32_bf16(k1, qA1, zA, 0, 0, 0);
        sA[t] = zA;
        f32x4 zB = {};
        zB = __builtin_amdgcn_mfma_f32_16x16x32_bf16(k0, qB0, zB, 0, 0, 0);
        zB = __builtin_amdgcn_mfma_f32_16x16x32_bf16(k1, qB1, zB, 0, 0, 0);
        sB[t] = zB;
      }
      __builtin_amdgcn_s_setprio(0);
#pragma unroll
      for (int t = 0; t < 4; t++) {
        float a0 = __builtin_amdgcn_exp2f(sA[t][0]);
        float a1 = __builtin_amdgcn_exp2f(sA[t][1]);
        float a2 = __builtin_amdgcn_exp2f(sA[t][2]);
        float a3 = __builtin_amdgcn_exp2f(sA[t][3]);
        rsA += (a0 + a1) + (a2 + a3);
        uint2 pa;
        pa.x = pkbf2(a0, a1);
        pa.y = pkbf2(a2, a3);
        *(uint2*)((uint8_t*)PwA + lr * 128 + ((t * 32 + lg * 8) ^ swz)) = pa;
        float b0 = __builtin_amdgcn_exp2f(sB[t][0]);
        float b1 = __builtin_amdgcn_exp2f(sB[t][1]);
        float b2 = __builtin_amdgcn_exp2f(sB[t][2]);
        float b3 = __builtin_amdgcn_exp2f(sB[t][3]);
        rsB += (b0 + b1) + (b2 + b3);
        uint2 pb;
        pb.x = pkbf2(b0, b1);
        pb.y = pkbf2(b2, b3);
        *(uint2*)((uint8_t*)PwB + lr * 128 + ((t * 32 + lg * 8) ^ swz)) = pb;
      }
      __builtin_amdgcn_wave_barrier();  // keep ds_reads after ds_writes (same-wave order)
      bf16x8 pA0 = *(const bf16x8*)((const uint8_t*)PwA + lr * 128 + ((lg << 4) ^ swz));
      bf16x8 pA1 = *(const bf16x8*)((const uint8_t*)PwA + lr * 128 + ((64 | (lg << 4)) ^ swz));
      bf16x8 pB0 = *(const bf16x8*)((const uint8_t*)PwB + lr * 128 + ((lg << 4) ^ swz));
      bf16x8 pB1 = *(const bf16x8*)((const uint8_t*)PwB + lr * 128 + ((64 | (lg << 4)) ^ swz));
      __builtin_amdgcn_s_setprio(1);
#pragma unroll
      for (int t = 0; t < 4; t++) {
        const uint8_t* rb = Vb + (16 * t + lr) * 128;
        bf16x8 v0 = *(const bf16x8*)(rb + ((lg << 4) ^ swz));
        bf16x8 v1 = *(const bf16x8*)(rb + ((64 | (lg << 4)) ^ swz));
        oA[t] = __builtin_amdgcn_mfma_f32_16x16x32_bf16(v0, pA0, oA[t], 0, 0, 0);
        oA[t] = __builtin_amdgcn_mfma_f32_16x16x32_bf16(v1, pA1, oA[t], 0, 0, 0);
        oB[t] = __builtin_amdgcn_mfma_f32_16x16x32_bf16(v0, pB0, oB[t], 0, 0, 0);
        oB[t] = __builtin_amdgcn_mfma_f32_16x16x32_bf16(v1, pB1, oB[t], 0, 0, 0);
      }
      __builtin_amdgcn_s_setprio(0);
      if (s2 == 0) __builtin_amdgcn_wave_barrier();  // P reuse: reads before next writes
    }
    __syncthreads();  // drains stage vmcnt + all waves done reading cur
  }
  rsA += __shfl_xor(rsA, 16);
  rsA += __shfl_xor(rsA, 32);
  rsB += __shfl_xor(rsB, 16);
  rsB += __shfl_xor(rsB, 32);
  float invA = 1.f / rsA, invB = 1.f / rsB;
  uint16_t* orowA = outb + (size_t)(b * 2048 + qbase + lr) * 1024 + h * 64;
  uint16_t* orowB = orowA + (size_t)16 * 1024;
#pragma unroll
  for (int t = 0; t < 4; t++) {
    uint2 ra;
    ra.x = pkbf2(oA[t][0] * invA, oA[t][1] * invA);
    ra.y = pkbf2(oA[t][2] * invA, oA[t][3] * invA);
    *(uint2*)(orowA + t * 16 + lg * 4) = ra;
    uint2 rb2;
    rb2.x = pkbf2(oB[t][0] * invB, oB[t][1] * invB);
    rb2.y = pkbf2(oB[t][2] * invB, oB[t][3] * invB);
    *(uint2*)(orowB + t * 16 + lg * 4) = rb2;
  }
}

// ----------------------------------------------------- LayerNorm(x + r0 [+ r1])
// XBF: xr is bf16; RBF: r0/r1 are bf16 (split-K partials stored bf16)
template <int XBF, int RBF, int WF32, int WB16, int NR>
__global__ __launch_bounds__(256) void ln_res(
    const void* __restrict__ xr, const void* __restrict__ r0,
    const void* __restrict__ r1, const float* __restrict__ gam,
    const float* __restrict__ bet, float* __restrict__ of32,
    uint16_t* __restrict__ ob16) {
  int row = blockIdx.x, t = threadIdx.x;
  int w = t >> 6, l = t & 63;
  auto ld4bf = [&](const void* p, float& a, float& b, float& c, float& d) {
    uint2 u = ((const uint2*)((const uint16_t*)p + (size_t)row * 1024))[t];
    a = __uint_as_float((u.x & 0xffffu) << 16);
    b = __uint_as_float(u.x & 0xffff0000u);
    c = __uint_as_float((u.y & 0xffffu) << 16);
    d = __uint_as_float(u.y & 0xffff0000u);
  };
  float v0, v1, v2, v3;
  if (XBF) {
    ld4bf(xr, v0, v1, v2, v3);
  } else {
    float4 xv = ((const float4*)((const float*)xr + (size_t)row * 1024))[t];
    v0 = xv.x; v1 = xv.y; v2 = xv.z; v3 = xv.w;
  }
  float r0a, r0b, r0c, r0d;
  if (RBF) {
    ld4bf(r0, r0a, r0b, r0c, r0d);
  } else {
    float4 rv = ((const float4*)((const float*)r0 + (size_t)row * 1024))[t];
    r0a = rv.x; r0b = rv.y; r0c = rv.z; r0d = rv.w;
  }
  v0 += r0a; v1 += r0b; v2 += r0c; v3 += r0d;
  if (NR == 2) {
    float r1a, r1b, r1c, r1d;
    if (RBF) {
      ld4bf(r1, r1a, r1b, r1c, r1d);
    } else {
      float4 rv = ((const float4*)((const float*)r1 + (size_t)row * 1024))[t];
      r1a = rv.x; r1b = rv.y; r1c = rv.z; r1d = rv.w;
    }
    v0 += r1a; v1 += r1b; v2 += r1c; v3 += r1d;
  }
  float s = v0 + v1 + v2 + v3;
  float sq = v0 * v0 + v1 * v1 + v2 * v2 + v3 * v3;
#pragma unroll
  for (int d = 1; d < 64; d <<= 1) {
    s += __shfl_xor(s, d);
    sq += __shfl_xor(sq, d);
  }
  __shared__ float red[8];
  if (l == 0) { red[w] = s; red[4 + w] = sq; }
  __syncthreads();
  s = red[0] + red[1] + red[2] + red[3];
  sq = red[4] + red[5] + red[6] + red[7];
  float mean = s * (1.f / 1024.f);
  float var = sq * (1.f / 1024.f) - mean * mean;
  float rstd = rsqrtf(var + 1e-5f);
  float4 gv = ((const float4*)gam)[t];
  float4 bv = ((const float4*)bet)[t];
  float y0 = (v0 - mean) * rstd * gv.x + bv.x;
  float y1 = (v1 - mean) * rstd * gv.y + bv.y;
  float y2 = (v2 - mean) * rstd * gv.z + bv.z;
  float y3 = (v3 - mean) * rstd * gv.w + bv.w;
  if (WF32) {
    float4 yv; yv.x = y0; yv.y = y1; yv.z = y2; yv.w = y3;
    ((float4*)(of32 + (size_t)row * 1024))[t] = yv;
  }
  if (WB16) {
    uint2 r;
    r.x = pkbf2(y0, y1);
    r.y = pkbf2(y2, y3);
    ((uint2*)(ob16 + (size_t)row * 1024))[t] = r;
  }
}

// ---------------------------------------------------------------- workspace map
static constexpr size_t OFF_XB    = 0;                          // 8 MB x_bf16; reused: attn_out
static constexpr size_t OFF_WQKVT = (size_t)8 << 20;            // 6 MB [3072][1024]
static constexpr size_t OFF_WOT   = (size_t)14 << 20;           // 2 MB [1024][1024]
static constexpr size_t OFF_W1T   = (size_t)16 << 20;           // 8 MB [4096][1024]
static constexpr size_t OFF_W2T   = (size_t)24 << 20;           // 8 MB [1024][4096]
static constexpr size_t OFF_BIAS  = (size_t)32 << 20;           // 12 KB f32 (pad 64K)
static constexpr size_t OFF_QKV   = OFF_BIAS + ((size_t)64 << 10);  // 24 MB; +VT reused: H (32MB)
static constexpr size_t OFF_VT    = OFF_QKV + ((size_t)24 << 20);   // 8 MB [32][64][2048]
static constexpr size_t OFF_PROJ  = OFF_VT + ((size_t)8 << 20);     // 8 MB bf16 (split-K partial 0)
static constexpr size_t OFF_LN1B  = OFF_PROJ + ((size_t)16 << 20);  // 8 MB bf16 trunk
static constexpr size_t OFF_PROJ2 = OFF_LN1B + ((size_t)8 << 20);   // 8 MB bf16 (split-K partial 1)
// total ~96 MB

extern "C" void kernel_launch(void* const* d_in, const int* in_sizes, int n_in,
                              void* d_out, int out_size, void* d_ws, size_t ws_size,
                              hipStream_t stream) {
  const float* x   = (const float*)d_in[0];
  const float* Wq  = (const float*)d_in[1];
  const float* bq  = (const float*)d_in[2];
  const float* Wk  = (const float*)d_in[3];
  const float* bk  = (const float*)d_in[4];
  const float* Wv  = (const float*)d_in[5];
  const float* bv  = (const float*)d_in[6];
  const float* Wo  = (const float*)d_in[7];
  const float* bo  = (const float*)d_in[8];
  const float* W1  = (const float*)d_in[9];
  const float* b1  = (const float*)d_in[10];
  const float* W2  = (const float*)d_in[11];
  const float* b2  = (const float*)d_in[12];
  const float* g1  = (const float*)d_in[13];
  const float* be1 = (const float*)d_in[14];
  const float* g2  = (const float*)d_in[15];
  const float* be2 = (const float*)d_in[16];
  float* out = (float*)d_out;
  uint8_t* ws = (uint8_t*)d_ws;

  uint16_t* xb    = (uint16_t*)(ws + OFF_XB);
  uint16_t* wqkt  = (uint16_t*)(ws + OFF_WQKVT);
  uint16_t* wot   = (uint16_t*)(ws + OFF_WOT);
  uint16_t* w1t   = (uint16_t*)(ws + OFF_W1T);
  uint16_t* w2t   = (uint16_t*)(ws + OFF_W2T);
  float*    bqkv  = (float*)(ws + OFF_BIAS);
  uint16_t* qkvb  = (uint16_t*)(ws + OFF_QKV);
  uint16_t* vt    = (uint16_t*)(ws + OFF_VT);
  uint16_t* proj  = (uint16_t*)(ws + OFF_PROJ);
  uint16_t* proj2 = (uint16_t*)(ws + OFF_PROJ2);
  uint16_t* ln1b  = (uint16_t*)(ws + OFF_LN1B);
  uint16_t* attnb = (uint16_t*)(ws + OFF_XB);   // alias: xb dead after QKV gemm
  uint16_t* hbuf  = (uint16_t*)(ws + OFF_QKV);  // alias: qkv+vt dead after attention

  // 1. cast x to bf16
  cast_bf16_kernel<<<4096, 256, 0, stream>>>(x, xb, 4096 * 1024 / 4);
  // 2. transpose weights to bf16 [N][K]
  transpose_w3<<<dim3(32, 32, 3), 256, 0, stream>>>(Wq, Wk, Wv, wqkt);
  transpose_w<<<dim3(32, 32), 256, 0, stream>>>(Wo, wot, 1024, 1024);
  transpose_w<<<dim3(128, 32), 256, 0, stream>>>(W1, w1t, 1024, 4096);
  transpose_w<<<dim3(32, 128), 256, 0, stream>>>(W2, w2t, 4096, 1024);
  concat3<<<12, 256, 0, stream>>>(bq, bk, bv, bqkv);
  // 3. fused QKV projection (BK=32: 768 blocks = exact 3/CU fit)
  gemm_bt<1, 1, 32><<<768, 256, 0, stream>>>(xb, wqkt, bqkv, qkvb, nullptr,
                                             4096, 3072, 1024, 24);
  // 4. V transpose per head
  transpose_v<<<dim3(64, 2, 32), 256, 0, stream>>>(qkvb, vt);
  // 5. fused attention (512 blocks, 16x16 MFMA, KVBLK=128)
  attn_fused<<<512, 256, 0, stream>>>(qkvb, vt, attnb);
  // 6. output projection, split-K x2, BK=64 -> bf16 partials
  gemm_bt<1, 2, 64><<<512, 256, 0, stream>>>(attnb, wot, bo, proj, proj2,
                                             4096, 1024, 1024, 8);
  // 7. LN1(x + proj + proj2) -> bf16 trunk only
  ln_res<0, 1, 0, 1, 2><<<4096, 256, 0, stream>>>(x, proj, proj2, g1, be1,
                                                  nullptr, ln1b);
  // 8. MLP1 + relu -> bf16, 256x256 phase-split schedule (256 blocks, 1/CU)
  gemm256<2><<<256, 512, 0, stream>>>(ln1b, w1t, b1, hbuf, 4096, 4096, 1024, 16);
  // 9. MLP2, split-K x2, BK=64 -> bf16 partials
  gemm_bt<1, 2, 64><<<512, 256, 0, stream>>>(hbuf, w2t, b2, proj, proj2,
                                             4096, 1024, 4096, 8);
  // 10. LN2(ln1b + proj + proj2) -> d_out fp32
  ln_res<1, 1, 1, 0, 2><<<4096, 256, 0, stream>>>(ln1b, proj, proj2, g2, be2,
                                                  out, nullptr);
}

// Round 15
// 211.080 us; speedup vs baseline: 1.1286x; 1.0315x over previous
//
#include <hip/hip_runtime.h>
#include <hip/hip_bf16.h>
#include <cstdint>

#define DEV __device__ __forceinline__

typedef __attribute__((ext_vector_type(8))) __bf16 bf16x8;
typedef __attribute__((ext_vector_type(4))) float f32x4;

// fp32 -> bf16 via HW cvt (single v_cvt instruction)
DEV uint16_t f2b(float f) {
  __hip_bfloat16 h = __float2bfloat16(f);
  return *(uint16_t*)&h;
}
// pack two floats into a bf16x2 word
DEV uint32_t pkbf2(float a, float b) {
  return (uint32_t)f2b(a) | ((uint32_t)f2b(b) << 16);
}

// async global->LDS, 16B per lane. LDS base must be wave-uniform; HW writes
// base + lane*16. Global source address is per-lane.
DEV void gload_lds16(const void* g, void* l) {
  __builtin_amdgcn_global_load_lds(
      (const __attribute__((address_space(1))) void*)g,
      (__attribute__((address_space(3))) void*)l, 16, 0, 0);
}

// scale a bf16x8 by a constant (via fp32, RNE back to bf16)
DEV bf16x8 scale8(bf16x8 v, float sc) {
  union { bf16x8 b; uint16_t u[8]; } in, out;
  in.b = v;
#pragma unroll
  for (int i = 0; i < 8; i++) {
    float x = __uint_as_float(((uint32_t)in.u[i]) << 16);
    out.u[i] = f2b(x * sc);
  }
  return out.b;
}

// ------------------------------------------------------- merged prep kernel
// One dispatch replacing: cast_x, transpose(Wq|Wk|Wv), transpose(Wo),
// transpose(W1), transpose(W2), concat3(biases). Role decoded from blockIdx.
// blocks: [0,4096) cast | [4096,7168) w3 | [7168,8192) Wo | [8192,12288) W1
//         | [12288,16384) W2 | [16384,16396) concat
__global__ __launch_bounds__(256) void prep_all(
    const float* __restrict__ x, uint16_t* __restrict__ xb,
    const float* __restrict__ Wq, const float* __restrict__ Wk,
    const float* __restrict__ Wv, uint16_t* __restrict__ wqkt,
    const float* __restrict__ Wo, uint16_t* __restrict__ wot,
    const float* __restrict__ W1, uint16_t* __restrict__ w1t,
    const float* __restrict__ W2, uint16_t* __restrict__ w2t,
    const float* __restrict__ bq, const float* __restrict__ bk,
    const float* __restrict__ bv, float* __restrict__ bqkv) {
  __shared__ float t[32][33];
  int bid = blockIdx.x, tid = threadIdx.x;
  if (bid < 4096) {               // ---- cast x -> bf16
    int i = bid * 256 + tid;
    float4 v = ((const float4*)x)[i];
    uint2 r;
    r.x = pkbf2(v.x, v.y);
    r.y = pkbf2(v.z, v.w);
    ((uint2*)xb)[i] = r;
    return;
  }
  if (bid >= 16384) {             // ---- bias concat
    int i = (bid - 16384) * 256 + tid;
    if (i < 3072)
      bqkv[i] = i < 1024 ? bq[i] : (i < 2048 ? bk[i - 1024] : bv[i - 2048]);
    return;
  }
  // ---- weight transpose fp32[R][C] -> bf16[C][R]
  const float* src;
  uint16_t* dst;
  int R, C, bx, by;
  if (bid < 8192) {
    int local = bid - 4096;
    if (local < 3072) {           // Wq|Wk|Wv (1024x1024 each)
      int z = local >> 10, rem = local & 1023;
      src = z == 0 ? Wq : (z == 1 ? Wk : Wv);
      dst = wqkt + (size_t)z * 1024 * 1024;
      R = 1024; C = 1024; bx = rem & 31; by = rem >> 5;
    } else {                      // Wo
      int rem = local - 3072;
      src = Wo; dst = wot; R = 1024; C = 1024; bx = rem & 31; by = rem >> 5;
    }
  } else if (bid < 12288) {       // W1: [1024][4096] -> [4096][1024]
    int rem = bid - 8192;
    src = W1; dst = w1t; R = 1024; C = 4096; bx = rem & 127; by = rem >> 7;
  } else {                        // W2: [4096][1024] -> [1024][4096]
    int rem = bid - 12288;
    src = W2; dst = w2t; R = 4096; C = 1024; bx = rem & 31; by = rem >> 5;
  }
  int c0 = bx * 32, r0 = by * 32;
  int tx = tid & 31, ty = tid >> 5;  // 32 x 8
#pragma unroll
  for (int i = 0; i < 4; i++)
    t[ty + 8 * i][tx] = src[(size_t)(r0 + ty + 8 * i) * C + c0 + tx];
  __syncthreads();
#pragma unroll
  for (int i = 0; i < 4; i++)
    dst[(size_t)(c0 + ty + 8 * i) * R + r0 + tx] = f2b(t[tx][ty + 8 * i]);
}

// ------------------------------------- V transpose: qkv[t][2048+h*64+d] -> Vt[bh][d][s]
__global__ __launch_bounds__(256) void transpose_v(
    const uint16_t* __restrict__ qkv, uint16_t* __restrict__ Vt) {
  __shared__ uint16_t t[32][33];
  int bh = blockIdx.z, b = bh >> 4, h = bh & 15;
  int s0 = blockIdx.x * 32, d0 = blockIdx.y * 32;
  int tx = threadIdx.x & 31, ty = threadIdx.x >> 5;
#pragma unroll
  for (int i = 0; i < 4; i++)
    t[ty + 8 * i][tx] =
        qkv[(size_t)(b * 2048 + s0 + ty + 8 * i) * 3072 + 2048 + h * 64 + d0 + tx];
  __syncthreads();
#pragma unroll
  for (int i = 0; i < 4; i++)
    Vt[((size_t)bh * 64 + d0 + ty + 8 * i) * 2048 + s0 + tx] = t[tx][ty + 8 * i];
}

// ------------------------------------------------------------------------- GEMM
// 128x128 tile, 4 waves, BK=32 linear / BK=64 swizzled, 2-phase pipeline.
// NSPLIT=2: K halved; split sp writes partial sp (contiguous base Cv + sp*M*N).
// MODE: 0 = fp32 out, 1 = bf16 out, 2 = bf16 out + relu
template <int MODE, int NSPLIT, int BK>
__global__ __launch_bounds__(256) void gemm_bt(
    const uint16_t* __restrict__ A, const uint16_t* __restrict__ Bt,
    const float* __restrict__ bias, void* __restrict__ Cv,
    int M, int N, int K, int nx) {
  __shared__ uint16_t As[2][128 * BK];
  __shared__ uint16_t Bs[2][128 * BK];
  int nwg = gridDim.x, bid = blockIdx.x;
  int cpx = nwg >> 3;
  int swzb = (bid & 7) * cpx + (bid >> 3);  // XCD (bid&7) owns contiguous chunk
  int ntile = nwg / NSPLIT;
  int sp = swzb / ntile, r = swzb % ntile;
  int n0 = (r % nx) * 128, m0 = (r / nx) * 128;
  int Klen = K / NSPLIT;
  int tid = threadIdx.x, w = tid >> 6, l = tid & 63;
  int wr = w >> 1, wc = w & 1;
  int lr = l & 15, lg = l >> 4, lk8 = lg * 8;
  f32x4 acc[4][4] = {};
  const uint16_t* Ab = A + (size_t)m0 * K + sp * Klen;
  const uint16_t* Bb = Bt + (size_t)n0 * K + sp * Klen;

  auto stage = [&](int buf, int k0) {
    if (BK == 32) {
#pragma unroll
      for (int i = 0; i < 2; i++) {
        int c = 2 * w + i;             // 8 chunks of 16 rows
        int rr = c * 16 + (l >> 2);
        gload_lds16(Ab + (size_t)rr * K + k0 + (l & 3) * 8, &As[buf][c * 512]);
        gload_lds16(Bb + (size_t)rr * K + k0 + (l & 3) * 8, &Bs[buf][c * 512]);
      }
    } else {
      int colb = (((l & 7) ^ ((l >> 3) & 7)) << 4);  // inverse-swizzled source
#pragma unroll
      for (int i = 0; i < 4; i++) {
        int c = 4 * w + i;             // 16 chunks of 8 rows
        int rr = c * 8 + (l >> 3);
        gload_lds16((const uint8_t*)(Ab + (size_t)rr * K + k0) + colb,
                    &As[buf][c * 512]);
        gload_lds16((const uint8_t*)(Bb + (size_t)rr * K + k0) + colb,
                    &Bs[buf][c * 512]);
      }
    }
  };

  stage(0, 0);
  __syncthreads();

  for (int k0 = 0; k0 < Klen; k0 += BK) {
    int cur = (k0 / BK) & 1;
    if (k0 + BK < Klen) stage(cur ^ 1, k0 + BK);  // prefetch next tile
    if (BK == 32) {
      bf16x8 af[4], bf[4];
#pragma unroll
      for (int m = 0; m < 4; m++)
        af[m] = *(const bf16x8*)&As[cur][(wr * 64 + m * 16 + lr) * 32 + lk8];
#pragma unroll
      for (int n = 0; n < 4; n++)
        bf[n] = *(const bf16x8*)&Bs[cur][(wc * 64 + n * 16 + lr) * 32 + lk8];
#pragma unroll
      for (int m = 0; m < 4; m++)
#pragma unroll
        for (int n = 0; n < 4; n++)
          acc[m][n] = __builtin_amdgcn_mfma_f32_16x16x32_bf16(af[m], bf[n], acc[m][n], 0, 0, 0);
    } else {
      int sw = (lr & 7) << 4;
#pragma unroll
      for (int ks = 0; ks < 2; ks++) {
        int off = ((ks << 6) | (lg << 4)) ^ sw;  // swizzled read (matches source)
        bf16x8 af[4], bf[4];
#pragma unroll
        for (int m = 0; m < 4; m++)
          af[m] = *(const bf16x8*)((const uint8_t*)&As[cur][(wr * 64 + m * 16 + lr) * 64] + off);
#pragma unroll
        for (int n = 0; n < 4; n++)
          bf[n] = *(const bf16x8*)((const uint8_t*)&Bs[cur][(wc * 64 + n * 16 + lr) * 64] + off);
#pragma unroll
        for (int m = 0; m < 4; m++)
#pragma unroll
          for (int n = 0; n < 4; n++)
            acc[m][n] = __builtin_amdgcn_mfma_f32_16x16x32_bf16(af[m], bf[n], acc[m][n], 0, 0, 0);
      }
    }
    __syncthreads();  // drains prefetch vmcnt + all waves done with cur
  }

  int g4 = lg * 4;
#pragma unroll
  for (int m = 0; m < 4; m++) {
    int row = m0 + wr * 64 + m * 16 + g4;
#pragma unroll
    for (int n = 0; n < 4; n++) {
      int col = n0 + wc * 64 + n * 16 + lr;
      float bv = (NSPLIT == 1 || sp == 0) ? bias[col] : 0.f;
#pragma unroll
      for (int j = 0; j < 4; j++) {
        float v = acc[m][n][j] + bv;
        if (MODE == 2) v = fmaxf(v, 0.f);
        size_t idx = (size_t)sp * M * N + (size_t)(row + j) * N + col;
        if (MODE == 0) ((float*)Cv)[idx] = v;
        else           ((uint16_t*)Cv)[idx] = f2b(v);
      }
    }
  }
}

// ---------------------------------------------------- GEMM 256x256, phase-split
// (round-12 verified schedule) + NSPLIT: split-K partials, contiguous base.
// 512 thr = 8 waves, BK=64, 4 phases/K-tile, counted vmcnt drain at phase 3.
template <int MODE, int NSPLIT>
__global__ __launch_bounds__(512, 2) void gemm256(
    const uint16_t* __restrict__ A, const uint16_t* __restrict__ Bt,
    const float* __restrict__ bias, void* __restrict__ Cv,
    int M, int N, int K, int nx) {
  __shared__ uint16_t As[2][256 * 64];
  __shared__ uint16_t Bs[2][256 * 64];
  int nwg = gridDim.x, bid = blockIdx.x;
  int cpx = nwg >> 3;
  int swzb = (bid & 7) * cpx + (bid >> 3);
  int ntile = nwg / NSPLIT;
  int sp = swzb / ntile, rr0 = swzb % ntile;
  int n0 = (rr0 % nx) * 256, m0 = (rr0 / nx) * 256;
  int Klen = K / NSPLIT;
  int tid = threadIdx.x, w = tid >> 6, l = tid & 63;
  int wr = w >> 2, wc = w & 3;
  int lr = l & 15, lg = l >> 4;
  f32x4 acc[8][4] = {};
  const uint16_t* Ab = A + (size_t)m0 * K + sp * Klen;
  const uint16_t* Bb = Bt + (size_t)n0 * K + sp * Klen;
  int colb = (((l & 7) ^ (l >> 3)) << 4);  // inverse-swizzled source col
  int srl = l >> 3;                        // lane sub-row 0..7

  auto stageH = [&](int buf, int k0, int h) {
    const uint16_t* base = (h < 2) ? Ab : Bb;
    uint16_t* lds = (h < 2) ? &As[buf][0] : &Bs[buf][0];
    int hh = (h & 1) * 128;
#pragma unroll
    for (int j = 0; j < 2; j++) {
      int rr = hh + j * 64 + w * 8;  // wave-uniform row base
      gload_lds16((const uint8_t*)(base + (size_t)(rr + srl) * K + k0) + colb,
                  &lds[rr * 64]);
    }
  };

#pragma unroll
  for (int h = 0; h < 4; h++) stageH(0, 0, h);
  asm volatile("s_waitcnt vmcnt(0)" ::: "memory");
  __builtin_amdgcn_s_barrier();

  int nt = Klen >> 6;
  int swr = (lr & 7) << 4;
  for (int t = 0; t < nt; t++) {
    int buf = t & 1;
    bf16x8 bfr[2][4];
#pragma unroll
    for (int ks = 0; ks < 2; ks++) {
#pragma unroll
      for (int mq = 0; mq < 2; mq++) {
        const int ph = ks * 2 + mq;
        int off = ((ks << 6) | (lg << 4)) ^ swr;
        bf16x8 af[4];
#pragma unroll
        for (int m = 0; m < 4; m++) {
          int row = wr * 128 + (mq * 4 + m) * 16 + lr;
          af[m] = *(const bf16x8*)((const uint8_t*)&As[buf][row * 64] + off);
        }
        if (mq == 0) {
#pragma unroll
          for (int n = 0; n < 4; n++) {
            int row = wc * 64 + n * 16 + lr;
            bfr[ks][n] = *(const bf16x8*)((const uint8_t*)&Bs[buf][row * 64] + off);
          }
        }
        if (t + 1 < nt) {
          if (ph == 0) { stageH(buf ^ 1, (t + 1) * 64, 0); stageH(buf ^ 1, (t + 1) * 64, 1); }
          if (ph == 1) { stageH(buf ^ 1, (t + 1) * 64, 2); stageH(buf ^ 1, (t + 1) * 64, 3); }
        }
        __builtin_amdgcn_s_barrier();
        asm volatile("s_waitcnt lgkmcnt(0)" ::: "memory");
        __builtin_amdgcn_sched_barrier(0);
        __builtin_amdgcn_s_setprio(1);
#pragma unroll
        for (int m = 0; m < 4; m++)
#pragma unroll
          for (int n = 0; n < 4; n++)
            acc[mq * 4 + m][n] = __builtin_amdgcn_mfma_f32_16x16x32_bf16(
                af[m], bfr[ks][n], acc[mq * 4 + m][n], 0, 0, 0);
        __builtin_amdgcn_s_setprio(0);
        if (ph == 3) asm volatile("s_waitcnt vmcnt(0)" ::: "memory");  // t+1 loads done
        __builtin_amdgcn_s_barrier();
      }
    }
  }

#pragma unroll
  for (int m = 0; m < 8; m++) {
    int row = m0 + wr * 128 + m * 16 + lg * 4;
#pragma unroll
    for (int n = 0; n < 4; n++) {
      int col = n0 + wc * 64 + n * 16 + lr;
      float bv = (NSPLIT == 1 || sp == 0) ? bias[col] : 0.f;
#pragma unroll
      for (int j = 0; j < 4; j++) {
        float v = acc[m][n][j] + bv;
        if (MODE == 2) v = fmaxf(v, 0.f);
        size_t idx = (size_t)sp * M * N + (size_t)(row + j) * N + col;
        if (MODE == 0) ((float*)Cv)[idx] = v;
        else           ((uint16_t*)Cv)[idx] = f2b(v);
      }
    }
  }
}

// --------------------------------------------------------------- fused attention
// (round-11/12 proven: 512 blocks, 4 waves, 2 Q-frags/wave, 16x16 MFMA,
// KVBLK=128 double-buffered, XOR-swizzle, no-max softmax, deferred denominator)
__global__ __launch_bounds__(256, 2) void attn_fused(
    const uint16_t* __restrict__ qkv, const uint16_t* __restrict__ Vt,
    uint16_t* __restrict__ outb) {
  constexpr int LQ = 3072;
  constexpr float SC = 0.18033688f;  // 0.125 * log2(e)
  int L = blockIdx.x;
  int qb = (L >> 3) & 15;
  int bh = (L & 7) + 8 * (L >> 7);
  int b = bh >> 4, h = bh & 15;
  int w = threadIdx.x >> 6, l = threadIdx.x & 63;
  int lr = l & 15, lg = l >> 4;
  int qbase = qb * 128 + w * 32;

  __shared__ uint16_t Kbuf[2][2][64 * 64];  // [dbuf][sub][key-row][d]
  __shared__ uint16_t Vbuf[2][2][64 * 64];  // [dbuf][sub][d-row][key]
  __shared__ uint16_t Plds[4][2][16 * 64];  // per-wave, per-qfrag P tiles
  uint16_t* PwA = &Plds[w][0][0];
  uint16_t* PwB = &Plds[w][1][0];

  const uint16_t* qrowA = qkv + (size_t)(b * 2048 + qbase + lr) * LQ + h * 64;
  const uint16_t* qrowB = qrowA + (size_t)16 * LQ;
  bf16x8 qA0 = scale8(*(const bf16x8*)(qrowA + lg * 8), SC);
  bf16x8 qA1 = scale8(*(const bf16x8*)(qrowA + 32 + lg * 8), SC);
  bf16x8 qB0 = scale8(*(const bf16x8*)(qrowB + lg * 8), SC);
  bf16x8 qB1 = scale8(*(const bf16x8*)(qrowB + 32 + lg * 8), SC);

  float rsA = 0.f, rsB = 0.f;
  f32x4 oA[4] = {}, oB[4] = {};

  const uint8_t* kq = (const uint8_t*)qkv;
  const uint8_t* vq = (const uint8_t*)Vt;
  int colb = (((l & 7) ^ ((l >> 3) & 7)) << 4);
  int Rl = w * 16 + (l >> 3);

  auto stageKV = [&](int buf, int kb) {
#pragma unroll
    for (int s2 = 0; s2 < 2; s2++) {
#pragma unroll
      for (int c2 = 0; c2 < 2; c2++) {
        int R = Rl + c2 * 8;
        const uint8_t* ks =
            kq + ((size_t)(b * 2048 + kb + s2 * 64 + R) * LQ + 1024 + h * 64) * 2 + colb;
        gload_lds16(ks, &Kbuf[buf][s2][(w * 16 + c2 * 8) * 64]);
        const uint8_t* vs =
            vq + ((size_t)(bh * 64 + R) * 2048 + kb + s2 * 64) * 2 + colb;
        gload_lds16(vs, &Vbuf[buf][s2][(w * 16 + c2 * 8) * 64]);
      }
    }
  };

  stageKV(0, 0);
  __syncthreads();

  int swz = (lr & 7) << 4;
  for (int kb = 0; kb < 2048; kb += 128) {
    int cur = (kb >> 7) & 1;
    if (kb + 128 < 2048) stageKV(cur ^ 1, kb + 128);

#pragma unroll
    for (int s2 = 0; s2 < 2; s2++) {
      const uint8_t* Kb = (const uint8_t*)Kbuf[cur][s2];
      const uint8_t* Vb = (const uint8_t*)Vbuf[cur][s2];
      f32x4 sA[4], sB[4];
      __builtin_amdgcn_s_setprio(1);
#pragma unroll
      for (int t = 0; t < 4; t++) {
        const uint8_t* rb = Kb + (16 * t + lr) * 128;
        bf16x8 k0 = *(const bf16x8*)(rb + ((lg << 4) ^ swz));
        bf16x8 k1 = *(const bf16x8*)(rb + ((64 | (lg << 4)) ^ swz));
        f32x4 zA = {};
        zA = __builtin_amdgcn_mfma_f32_16x16x32_bf16(k0, qA0, zA, 0, 0, 0);
        zA = __builtin_amdgcn_mfma_f32_16x16x32_bf16(k1, qA1, zA, 0, 0, 0);
        sA[t] = zA;
        f32x4 zB = {};
        zB = __builtin_amdgcn_mfma_f32_16x16x32_bf16(k0, qB0, zB, 0, 0, 0);
        zB = __builtin_amdgcn_mfma_f32_16x16x32_bf16(k1, qB1, zB, 0, 0, 0);
        sB[t] = zB;
      }
      __builtin_amdgcn_s_setprio(0);
#pragma unroll
      for (int t = 0; t < 4; t++) {
        float a0 = __builtin_amdgcn_exp2f(sA[t][0]);
        float a1 = __builtin_amdgcn_exp2f(sA[t][1]);
        float a2 = __builtin_amdgcn_exp2f(sA[t][2]);
        float a3 = __builtin_amdgcn_exp2f(sA[t][3]);
        rsA += (a0 + a1) + (a2 + a3);
        uint2 pa;
        pa.x = pkbf2(a0, a1);
        pa.y = pkbf2(a2, a3);
        *(uint2*)((uint8_t*)PwA + lr * 128 + ((t * 32 + lg * 8) ^ swz)) = pa;
        float b0 = __builtin_amdgcn_exp2f(sB[t][0]);
        float b1 = __builtin_amdgcn_exp2f(sB[t][1]);
        float b2 = __builtin_amdgcn_exp2f(sB[t][2]);
        float b3 = __builtin_amdgcn_exp2f(sB[t][3]);
        rsB += (b0 + b1) + (b2 + b3);
        uint2 pb;
        pb.x = pkbf2(b0, b1);
        pb.y = pkbf2(b2, b3);
        *(uint2*)((uint8_t*)PwB + lr * 128 + ((t * 32 + lg * 8) ^ swz)) = pb;
      }
      __builtin_amdgcn_wave_barrier();  // keep ds_reads after ds_writes (same-wave order)
      bf16x8 pA0 = *(const bf16x8*)((const uint8_t*)PwA + lr * 128 + ((lg << 4) ^ swz));
      bf16x8 pA1 = *(const bf16x8*)((const uint8_t*)PwA + lr * 128 + ((64 | (lg << 4)) ^ swz));
      bf16x8 pB0 = *(const bf16x8*)((const uint8_t*)PwB + lr * 128 + ((lg << 4) ^ swz));
      bf16x8 pB1 = *(const bf16x8*)((const uint8_t*)PwB + lr * 128 + ((64 | (lg << 4)) ^ swz));
      __builtin_amdgcn_s_setprio(1);
#pragma unroll
      for (int t = 0; t < 4; t++) {
        const uint8_t* rb = Vb + (16 * t + lr) * 128;
        bf16x8 v0 = *(const bf16x8*)(rb + ((lg << 4) ^ swz));
        bf16x8 v1 = *(const bf16x8*)(rb + ((64 | (lg << 4)) ^ swz));
        oA[t] = __builtin_amdgcn_mfma_f32_16x16x32_bf16(v0, pA0, oA[t], 0, 0, 0);
        oA[t] = __builtin_amdgcn_mfma_f32_16x16x32_bf16(v1, pA1, oA[t], 0, 0, 0);
        oB[t] = __builtin_amdgcn_mfma_f32_16x16x32_bf16(v0, pB0, oB[t], 0, 0, 0);
        oB[t] = __builtin_amdgcn_mfma_f32_16x16x32_bf16(v1, pB1, oB[t], 0, 0, 0);
      }
      __builtin_amdgcn_s_setprio(0);
      if (s2 == 0) __builtin_amdgcn_wave_barrier();  // P reuse: reads before next writes
    }
    __syncthreads();  // drains stage vmcnt + all waves done reading cur
  }
  rsA += __shfl_xor(rsA, 16);
  rsA += __shfl_xor(rsA, 32);
  rsB += __shfl_xor(rsB, 16);
  rsB += __shfl_xor(rsB, 32);
  float invA = 1.f / rsA, invB = 1.f / rsB;
  uint16_t* orowA = outb + (size_t)(b * 2048 + qbase + lr) * 1024 + h * 64;
  uint16_t* orowB = orowA + (size_t)16 * 1024;
#pragma unroll
  for (int t = 0; t < 4; t++) {
    uint2 ra;
    ra.x = pkbf2(oA[t][0] * invA, oA[t][1] * invA);
    ra.y = pkbf2(oA[t][2] * invA, oA[t][3] * invA);
    *(uint2*)(orowA + t * 16 + lg * 4) = ra;
    uint2 rb2;
    rb2.x = pkbf2(oB[t][0] * invB, oB[t][1] * invB);
    rb2.y = pkbf2(oB[t][2] * invB, oB[t][3] * invB);
    *(uint2*)(orowB + t * 16 + lg * 4) = rb2;
  }
}

// ------------------------------------------- LayerNorm(x + sum of NPART partials)
// XBF: xr is bf16. parts: NPART contiguous bf16 [4096][1024] partials.
template <int XBF, int WF32, int WB16, int NPART>
__global__ __launch_bounds__(256) void ln_res(
    const void* __restrict__ xr, const uint16_t* __restrict__ parts,
    const float* __restrict__ gam, const float* __restrict__ bet,
    float* __restrict__ of32, uint16_t* __restrict__ ob16) {
  int row = blockIdx.x, t = threadIdx.x;
  int w = t >> 6, l = t & 63;
  float v0, v1, v2, v3;
  if (XBF) {
    uint2 u = ((const uint2*)((const uint16_t*)xr + (size_t)row * 1024))[t];
    v0 = __uint_as_float((u.x & 0xffffu) << 16);
    v1 = __uint_as_float(u.x & 0xffff0000u);
    v2 = __uint_as_float((u.y & 0xffffu) << 16);
    v3 = __uint_as_float(u.y & 0xffff0000u);
  } else {
    float4 xv = ((const float4*)((const float*)xr + (size_t)row * 1024))[t];
    v0 = xv.x; v1 = xv.y; v2 = xv.z; v3 = xv.w;
  }
#pragma unroll
  for (int p = 0; p < NPART; p++) {
    uint2 u = ((const uint2*)(parts + (size_t)p * 4096 * 1024 +
                              (size_t)row * 1024))[t];
    v0 += __uint_as_float((u.x & 0xffffu) << 16);
    v1 += __uint_as_float(u.x & 0xffff0000u);
    v2 += __uint_as_float((u.y & 0xffffu) << 16);
    v3 += __uint_as_float(u.y & 0xffff0000u);
  }
  float s = v0 + v1 + v2 + v3;
  float sq = v0 * v0 + v1 * v1 + v2 * v2 + v3 * v3;
#pragma unroll
  for (int d = 1; d < 64; d <<= 1) {
    s += __shfl_xor(s, d);
    sq += __shfl_xor(sq, d);
  }
  __shared__ float red[8];
  if (l == 0) { red[w] = s; red[4 + w] = sq; }
  __syncthreads();
  s = red[0] + red[1] + red[2] + red[3];
  sq = red[4] + red[5] + red[6] + red[7];
  float mean = s * (1.f / 1024.f);
  float var = sq * (1.f / 1024.f) - mean * mean;
  float rstd = rsqrtf(var + 1e-5f);
  float4 gv = ((const float4*)gam)[t];
  float4 bv = ((const float4*)bet)[t];
  float y0 = (v0 - mean) * rstd * gv.x + bv.x;
  float y1 = (v1 - mean) * rstd * gv.y + bv.y;
  float y2 = (v2 - mean) * rstd * gv.z + bv.z;
  float y3 = (v3 - mean) * rstd * gv.w + bv.w;
  if (WF32) {
    float4 yv; yv.x = y0; yv.y = y1; yv.z = y2; yv.w = y3;
    ((float4*)(of32 + (size_t)row * 1024))[t] = yv;
  }
  if (WB16) {
    uint2 r;
    r.x = pkbf2(y0, y1);
    r.y = pkbf2(y2, y3);
    ((uint2*)(ob16 + (size_t)row * 1024))[t] = r;
  }
}

// ---------------------------------------------------------------- workspace map
static constexpr size_t OFF_XB    = 0;                          // 8 MB x_bf16; reused: attn_out
static constexpr size_t OFF_WQKVT = (size_t)8 << 20;            // 6 MB [3072][1024]
static constexpr size_t OFF_WOT   = (size_t)14 << 20;           // 2 MB [1024][1024]
static constexpr size_t OFF_W1T   = (size_t)16 << 20;           // 8 MB [4096][1024]
static constexpr size_t OFF_W2T   = (size_t)24 << 20;           // 8 MB [1024][4096]
static constexpr size_t OFF_BIAS  = (size_t)32 << 20;           // 12 KB f32 (pad 64K)
static constexpr size_t OFF_QKV   = OFF_BIAS + ((size_t)64 << 10);  // 24 MB; +VT reused: H (32MB)
static constexpr size_t OFF_VT    = OFF_QKV + ((size_t)24 << 20);   // 8 MB [32][64][2048]
static constexpr size_t OFF_PROJ  = OFF_VT + ((size_t)8 << 20);     // 32 MB: 4x bf16 partials
static constexpr size_t OFF_LN1B  = OFF_PROJ + ((size_t)32 << 20);  // 8 MB bf16 trunk
// total ~112 MB

extern "C" void kernel_launch(void* const* d_in, const int* in_sizes, int n_in,
                              void* d_out, int out_size, void* d_ws, size_t ws_size,
                              hipStream_t stream) {
  const float* x   = (const float*)d_in[0];
  const float* Wq  = (const float*)d_in[1];
  const float* bq  = (const float*)d_in[2];
  const float* Wk  = (const float*)d_in[3];
  const float* bk  = (const float*)d_in[4];
  const float* Wv  = (const float*)d_in[5];
  const float* bv  = (const float*)d_in[6];
  const float* Wo  = (const float*)d_in[7];
  const float* bo  = (const float*)d_in[8];
  const float* W1  = (const float*)d_in[9];
  const float* b1  = (const float*)d_in[10];
  const float* W2  = (const float*)d_in[11];
  const float* b2  = (const float*)d_in[12];
  const float* g1  = (const float*)d_in[13];
  const float* be1 = (const float*)d_in[14];
  const float* g2  = (const float*)d_in[15];
  const float* be2 = (const float*)d_in[16];
  float* out = (float*)d_out;
  uint8_t* ws = (uint8_t*)d_ws;

  uint16_t* xb    = (uint16_t*)(ws + OFF_XB);
  uint16_t* wqkt  = (uint16_t*)(ws + OFF_WQKVT);
  uint16_t* wot   = (uint16_t*)(ws + OFF_WOT);
  uint16_t* w1t   = (uint16_t*)(ws + OFF_W1T);
  uint16_t* w2t   = (uint16_t*)(ws + OFF_W2T);
  float*    bqkv  = (float*)(ws + OFF_BIAS);
  uint16_t* qkvb  = (uint16_t*)(ws + OFF_QKV);
  uint16_t* vt    = (uint16_t*)(ws + OFF_VT);
  uint16_t* proj  = (uint16_t*)(ws + OFF_PROJ);   // 4x contiguous partials
  uint16_t* ln1b  = (uint16_t*)(ws + OFF_LN1B);
  uint16_t* attnb = (uint16_t*)(ws + OFF_XB);   // alias: xb dead after QKV gemm
  uint16_t* hbuf  = (uint16_t*)(ws + OFF_QKV);  // alias: qkv+vt dead after attention

  // 1. merged prep: cast x, all weight transposes, bias concat (one dispatch)
  prep_all<<<16396, 256, 0, stream>>>(x, xb, Wq, Wk, Wv, wqkt, Wo, wot,
                                      W1, w1t, W2, w2t, bq, bk, bv, bqkv);
  // 2. fused QKV projection (BK=32: 768 blocks = exact 3/CU fit)
  gemm_bt<1, 1, 32><<<768, 256, 0, stream>>>(xb, wqkt, bqkv, qkvb,
                                             4096, 3072, 1024, 24);
  // 3. V transpose per head
  transpose_v<<<dim3(64, 2, 32), 256, 0, stream>>>(qkvb, vt);
  // 4. fused attention (512 blocks, 16x16 MFMA, KVBLK=128)
  attn_fused<<<512, 256, 0, stream>>>(qkvb, vt, attnb);
  // 5. output projection, split-K x2, BK=64 -> bf16 partials 0,1
  gemm_bt<1, 2, 64><<<512, 256, 0, stream>>>(attnb, wot, bo, proj,
                                             4096, 1024, 1024, 8);
  // 6. LN1(x + p0 + p1) -> bf16 trunk only
  ln_res<0, 0, 1, 2><<<4096, 256, 0, stream>>>(x, proj, g1, be1,
                                               nullptr, ln1b);
  // 7. MLP1 + relu -> bf16, 256x256 phase-split (256 blocks, 1/CU)
  gemm256<2, 1><<<256, 512, 0, stream>>>(ln1b, w1t, b1, hbuf,
                                         4096, 4096, 1024, 16);
  // 8. MLP2: 256x256 phase-split, split-K x4 -> bf16 partials 0..3 (256 blocks)
  gemm256<1, 4><<<256, 512, 0, stream>>>(hbuf, w2t, b2, proj,
                                         4096, 1024, 4096, 4);
  // 9. LN2(ln1b + p0 + p1 + p2 + p3) -> d_out fp32
  ln_res<1, 1, 0, 4><<<4096, 256, 0, stream>>>(ln1b, proj, g2, be2,
                                               out, nullptr);
}